// Round 2
// baseline (339.771 us; speedup 1.0000x reference)
//
#include <hip/hip_runtime.h>

// (B,C,D,H,W) = (2,64,32,64,64), R=2, NCH=125
#define B_ 2
#define C_ 64
#define D_ 32
#define H_ 64
#define W_ 64
#define NCH 125
#define HW_ (H_ * W_)              // 4096
#define DHW_ (D_ * HW_)            // 131072
#define CDHW_ (C_ * DHW_)          // 8388608

// Read-only zero sink: invalid halo rows point here instead of using masked
// loads. Never written; zero-initialized in the module image.
__device__ __attribute__((aligned(16))) const float g_zero[16] = {};

// Live offsets form an L: s=i+j in [-4..4], last-write winner is
//   s<=0 -> (i,j)=(s+2,-2): x2[y+dy][x+2], dy=-i in {-2..2}, channel s=-dy-2
//   s>=0 -> (i,j)=(2,s-2) : x2[y-2][x+2-s]
// ch = (5s+h) mod 125 -> live channels {0..22} u {103..124}; 23..102 are
// never written by the reference -> exactly zero.
// One kernel: block(16,16) covers (y-tile 16, full x), grid(4, D, B*5);
// blockIdx.z selects (b, depth-shift hh). Each thread: 4 voxels (float4),
// 9 spatial offsets, loop over c with branchless pointer-selected loads.
__global__ __launch_bounds__(256) void cv_all(const float* __restrict__ x1,
                                              const float* __restrict__ x2,
                                              float* __restrict__ out)
{
    const int tx = threadIdx.x;            // 0..15 -> x quad
    const int ty = threadIdx.y;            // 0..15 -> y row
    const int y  = blockIdx.x * 16 + ty;
    const int d  = blockIdx.y;
    const int bz = blockIdx.z;             // 0..9
    const int b  = bz / 5;
    const int hi = bz - b * 5;             // 0..4
    const int hh = hi - 2;                 // depth shift in [-2,2]
    const int x  = tx * 4;
    const int zd = d - hh;
    const bool zok = (zd >= 0) && (zd < D_);

    const float* zb  = g_zero + 8;         // reads at zb-2 .. zb+1 stay inside g_zero
    const float* x2b = x2 + (size_t)b * CDHW_ + (size_t)(zok ? zd : 0) * HW_;

    // Column pointers: P[k] -> (row y+k-2, col x+2), Q[k] -> (row, col x+4,
    // gated so cols 64/65 read zeros). Invalid rows -> zero sink, stride 0.
    const float* P[5]; int sP[5];
    const float* Q[5]; int sQ[5];
    const bool xhi = (tx < 15);
    const bool xlo = (tx > 0);
#pragma unroll
    for (int k = 0; k < 5; ++k) {
        const int  yy = y + k - 2;
        const bool v  = zok && (yy >= 0) && (yy < H_);
        P[k]  = v ? (x2b + yy * W_ + x + 2) : zb;
        sP[k] = v ? DHW_ : 0;
        const bool v2 = v && xhi;
        Q[k]  = v2 ? (x2b + yy * W_ + x + 4) : zb;
        sQ[k] = v2 ? DHW_ : 0;
    }
    // Row-part left pair (row y-2, cols x-2..x-1), gated by x>0.
    const bool vL = zok && (y >= 2) && xlo;
    const float* PL = vL ? (x2b + (y - 2) * W_ + x - 2) : zb;
    const int    sL = vL ? DHW_ : 0;

    const float* p1 = x1 + (size_t)b * CDHW_ + (size_t)d * HW_ + (size_t)(y * W_ + x);

    float acc[9][4];
#pragma unroll
    for (int k = 0; k < 9; ++k)
#pragma unroll
        for (int j = 0; j < 4; ++j) acc[k][j] = 0.f;

    for (int c = 0; c < C_; ++c) {
        const float4 a = *(const float4*)p1;
        float2 cA[5], cB[5];
#pragma unroll
        for (int k = 0; k < 5; ++k) {
            cA[k] = *(const float2*)(P[k]);        // cols x+2..x+3
            cB[k] = *(const float2*)(Q[k]);        // cols x+4..x+5 (or 0)
        }
        const float2 L = *(const float2*)(PL);     // row y-2, cols x-2..x-1 (or 0)
        const float2 M = *(const float2*)(P[0] - 2); // row y-2, cols x..x+1 (or 0)

        // column part: k -> dy=k-2, channel index ai = 4-k (s = -k)
#pragma unroll
        for (int k = 0; k < 5; ++k) {
            const int ai = 4 - k;
            acc[ai][0] += a.x * cA[k].x;
            acc[ai][1] += a.y * cA[k].y;
            acc[ai][2] += a.z * cB[k].x;
            acc[ai][3] += a.w * cB[k].y;
        }
        // row part: r8 = row y-2 cols x-2..x+5; s=1..4 -> acc[s+4],
        // voxel x+v uses col (x+v+2-s) = r8[4+v-s]
        const float r8[8] = {L.x, L.y, M.x, M.y, cA[0].x, cA[0].y, cB[0].x, cB[0].y};
#pragma unroll
        for (int s = 1; s <= 4; ++s) {
            const int ai = s + 4;
            acc[ai][0] += a.x * r8[4 - s];
            acc[ai][1] += a.y * r8[5 - s];
            acc[ai][2] += a.z * r8[6 - s];
            acc[ai][3] += a.w * r8[7 - s];
        }

        p1 += DHW_;
#pragma unroll
        for (int k = 0; k < 5; ++k) { P[k] += sP[k]; Q[k] += sQ[k]; }
        PL += sL;
    }

    // Epilogue: 9 live channels + this hi's 16 dead channels (23+16*hi ..).
    float* ob = out + (size_t)b * NCH * DHW_ + (size_t)d * HW_ + (size_t)(y * W_ + x);
    const float inv = 1.0f / 125.0f;
#pragma unroll
    for (int k = 0; k < 9; ++k) {
        const int s  = k - 4;
        int ch = 5 * s + hh;
        ch = (ch % NCH + NCH) % NCH;
        float4 v;
        v.x = acc[k][0] * inv;
        v.y = acc[k][1] * inv;
        v.z = acc[k][2] * inv;
        v.w = acc[k][3] * inv;
        *(float4*)(ob + (size_t)ch * DHW_) = v;
    }
    const float4 zero4 = make_float4(0.f, 0.f, 0.f, 0.f);
#pragma unroll
    for (int t = 0; t < 16; ++t) {
        const int ch = 23 + hi * 16 + t;
        *(float4*)(ob + (size_t)ch * DHW_) = zero4;
    }
}

extern "C" void kernel_launch(void* const* d_in, const int* in_sizes, int n_in,
                              void* d_out, int out_size, void* d_ws, size_t ws_size,
                              hipStream_t stream) {
    const float* x1 = (const float*)d_in[0];
    const float* x2 = (const float*)d_in[1];
    float* out = (float*)d_out;
    cv_all<<<dim3(H_ / 16, D_, B_ * 5), dim3(16, 16, 1), 0, stream>>>(x1, x2, out);
}

// Round 3
// 297.130 us; speedup vs baseline: 1.1435x; 1.1435x over previous
//
#include <hip/hip_runtime.h>

// (B,C,D,H,W) = (2,64,32,64,64), R=2, NCH=125
#define B_ 2
#define C_ 64
#define D_ 32
#define H_ 64
#define W_ 64
#define NCH 125
#define HW_ (H_ * W_)              // 4096
#define DHW_ (D_ * HW_)            // 131072
#define CDHW_ (C_ * DHW_)          // 8388608

#define BROWS 20                   // x2 tile rows: y0-2 .. y0+17
#define BSTR  72                   // padded row stride (floats); col q at idx 4+q
#define BUFSZ (BROWS * BSTR)       // 1440 floats per buffer

// Live offsets form an L: s=i+j in [-4..4], last-write winner is
//   s<=0 -> (i,j)=(s+2,-2): x2[y-dy... i.e. rows y-2..y+2, cols x+2..x+5
//   s>=0 -> (i,j)=(2,s-2) : row y-2, cols x+2-s
// ch=(5s+h) mod 125 -> live {0..22}u{103..124}; 23..102 identically zero.
// Block (16,16): y-tile 16, full x, one (b,hh,d). x2 tile double-buffered in
// LDS (halo-padded, invalid rows/cols stay zero); 2-deep global prefetch.
__global__ __launch_bounds__(256, 4) void cv_all(const float* __restrict__ x1,
                                                 const float* __restrict__ x2,
                                                 float* __restrict__ out)
{
    __shared__ float ldsB[2 * BUFSZ];

    const int tx  = threadIdx.x;           // 0..15 -> x quad
    const int ty  = threadIdx.y;           // 0..15 -> y row
    const int tid = ty * 16 + tx;
    const int bz  = blockIdx.x;            // (b,hh) FASTEST -> L2/L3 locality
    const int y0  = blockIdx.y * 16;
    const int d   = blockIdx.z;
    const int b   = bz / 5;
    const int hi  = bz - b * 5;            // 0..4
    const int hh  = hi - 2;                // depth shift in [-2,2]
    const int y   = y0 + ty;
    const int x   = tx * 4;
    const int zd  = d - hh;
    const bool zok = (zd >= 0) && (zd < D_);

    // Zero both buffers once: halo cols (idx 0..3, 68..71) and never-staged
    // rows remain zero for the whole kernel.
    {
        float4* p = (float4*)ldsB;
#pragma unroll
        for (int i = 0; i < 3; ++i) {
            const int idx = tid + i * 256;
            if (idx < 2 * BUFSZ / 4) p[idx] = make_float4(0.f, 0.f, 0.f, 0.f);
        }
    }

    // Staging geometry (c-independent). Valid global rows [g_lo, g_hi] are
    // contiguous in memory (full-x rows) -> perfectly coalesced float4 loads.
    const int g_lo  = max(0, y0 - 2);
    const int g_hi  = min(H_ - 1, y0 + 17);
    const int n4    = zok ? (g_hi - g_lo + 1) * 16 : 0;   // float4 count (<=320)
    const int r_off = g_lo - (y0 - 2);
    const float* sbase = x2 + (size_t)b * CDHW_ + (size_t)(zok ? zd : 0) * HW_
                            + (size_t)g_lo * W_;

    const int  i0 = tid;                   // staging slot 0
    const int  i1 = tid + 256;             // staging slot 1 (only if n4 > 256)
    const bool w0 = (i0 < n4);
    const bool w1 = (i1 < n4);
    const int  d0 = (r_off + (i0 >> 4)) * BSTR + 4 + (i0 & 15) * 4;   // 16B aligned
    const int  d1 = (r_off + ((w1 ? i1 : 0) >> 4)) * BSTR + 4 + (i1 & 15) * 4;

    const float* p1 = x1 + (size_t)b * CDHW_ + (size_t)d * HW_ + (size_t)(y * W_ + x);

    // ---- pipeline preload: stage(0) -> buf0; stage(1), x1(0), x1(1) in regs
    float4 s1a, s1b, a_cur, a_next;
    {
        float4 s0a, s0b;
        if (w0) s0a = *(const float4*)(sbase + (size_t)i0 * 4);
        if (w1) s0b = *(const float4*)(sbase + (size_t)i1 * 4);
        a_cur  = *(const float4*)p1;
        a_next = *(const float4*)(p1 + DHW_);
        if (w0) s1a = *(const float4*)(sbase + DHW_ + (size_t)i0 * 4);
        if (w1) s1b = *(const float4*)(sbase + DHW_ + (size_t)i1 * 4);
        __syncthreads();                       // zero-fill visible
        if (w0) *(float4*)(ldsB + d0) = s0a;
        if (w1) *(float4*)(ldsB + d1) = s0b;
        __syncthreads();                       // buf0 ready
    }

    float acc[9][4];
#pragma unroll
    for (int k = 0; k < 9; ++k)
#pragma unroll
        for (int j = 0; j < 4; ++j) acc[k][j] = 0.f;

#pragma unroll 2
    for (int c = 0; c < C_; ++c) {
        const int buf = c & 1;
        const int c2  = (c + 2) & (C_ - 1);    // wraps harmlessly at the tail

        // issue c+2 prefetches first (a full iteration of latency slack)
        float4 s2a, s2b;
        const float* sn = sbase + (size_t)c2 * DHW_;
        if (w0) s2a = *(const float4*)(sn + (size_t)i0 * 4);
        if (w1) s2b = *(const float4*)(sn + (size_t)i1 * 4);
        const float4 a  = a_cur;
        a_cur  = a_next;
        a_next = *(const float4*)(p1 + (size_t)c2 * DHW_);

        // ---- compute from ldsB[buf]
        const float* Bb = ldsB + buf * BUFSZ;
        float2 cA0, cB0;
#pragma unroll
        for (int k = 0; k < 5; ++k) {          // rows y-2..y+2, cols x+2..x+5
            const float* pr = Bb + (ty + k) * BSTR + (x + 6);
            const float2 cA = *(const float2*)pr;
            const float2 cB = *(const float2*)(pr + 2);
            if (k == 0) { cA0 = cA; cB0 = cB; }
            const int ai = 4 - k;              // s = -(k) ... channel acc index
            acc[ai][0] += a.x * cA.x;
            acc[ai][1] += a.y * cA.y;
            acc[ai][2] += a.z * cB.x;
            acc[ai][3] += a.w * cB.y;
        }
        {                                      // row y-2, cols x-2..x+1
            const float* pr0 = Bb + ty * BSTR + (x + 2);
            const float2 rl = *(const float2*)pr0;
            const float2 rm = *(const float2*)(pr0 + 2);
            const float r8[8] = {rl.x, rl.y, rm.x, rm.y,
                                 cA0.x, cA0.y, cB0.x, cB0.y};
#pragma unroll
            for (int s = 1; s <= 4; ++s) {     // voxel x+v uses r8[4+v-s]
                const int ai = s + 4;
                acc[ai][0] += a.x * r8[4 - s];
                acc[ai][1] += a.y * r8[5 - s];
                acc[ai][2] += a.z * r8[6 - s];
                acc[ai][3] += a.w * r8[7 - s];
            }
        }

        // ---- write stage(c+1) (loaded last iter -> vmcnt long satisfied)
        float* Bw = ldsB + (buf ^ 1) * BUFSZ;
        if (w0) *(float4*)(Bw + d0) = s1a;
        if (w1) *(float4*)(Bw + d1) = s1b;
        s1a = s2a;
        s1b = s2b;
        __syncthreads();
    }

    // ---- epilogue: 9 live channels + this hi's 16 dead channels
    float* ob = out + (size_t)b * NCH * DHW_ + (size_t)d * HW_ + (size_t)(y * W_ + x);
    const float inv = 1.0f / 125.0f;
#pragma unroll
    for (int k = 0; k < 9; ++k) {
        const int s  = k - 4;
        int ch = 5 * s + hh;
        ch = (ch % NCH + NCH) % NCH;
        float4 v;
        v.x = acc[k][0] * inv;
        v.y = acc[k][1] * inv;
        v.z = acc[k][2] * inv;
        v.w = acc[k][3] * inv;
        *(float4*)(ob + (size_t)ch * DHW_) = v;
    }
    const float4 zero4 = make_float4(0.f, 0.f, 0.f, 0.f);
#pragma unroll
    for (int t = 0; t < 16; ++t) {
        const int ch = 23 + hi * 16 + t;       // hi=0..4 -> 23..102 covered
        *(float4*)(ob + (size_t)ch * DHW_) = zero4;
    }
}

extern "C" void kernel_launch(void* const* d_in, const int* in_sizes, int n_in,
                              void* d_out, int out_size, void* d_ws, size_t ws_size,
                              hipStream_t stream) {
    const float* x1 = (const float*)d_in[0];
    const float* x2 = (const float*)d_in[1];
    float* out = (float*)d_out;
    // (b,hh) fastest -> blocks sharing x1/x2 slabs dispatch adjacently
    cv_all<<<dim3(B_ * 5, H_ / 16, D_), dim3(16, 16, 1), 0, stream>>>(x1, x2, out);
}

// Round 4
// 275.641 us; speedup vs baseline: 1.2327x; 1.0780x over previous
//
#include <hip/hip_runtime.h>

// (B,C,D,H,W) = (2,64,32,64,64), R=2, NCH=125
#define B_ 2
#define C_ 64
#define D_ 32
#define H_ 64
#define W_ 64
#define NCH 125
#define HW_ 4096
#define DHW_ 131072
#define CDHW_ 8388608

// Wave-private x2 tile: 8 rows (y-rows of wave ±2 halo), stride 68,
// layout: global col gc at dword idx gc+2 -> all compute reads 16B-aligned.
#define BSTR 68
#define TROWS 8
#define TBUF (TROWS * BSTR)        // 544 floats per buffer
#define WLDS (2 * TBUF)            // double-buffered, per wave

__device__ __attribute__((aligned(16))) const float g_zero[4] = {0.f, 0.f, 0.f, 0.f};

// Live offsets form an L: s=i+j in [-4..4], last-write winner is
//   s<=0 -> (i,j)=(s+2,-2): rows y-2..y+2, cols x+2..x+5   (channel s=-k)
//   s>=0 -> (i,j)=(2,s-2) : row y-2, cols x+2-s
// ch=(5s+h) mod 125 -> live {0..22}u{103..124}; 23..102 identically zero.
//
// Wave-autonomous: each 64-lane wave owns 4 y-rows, stages its own 8-row
// x2 tile into private LDS (dbuf), 3-deep global register prefetch.
// NO __syncthreads anywhere -> no vmcnt(0) barrier drains; per-wave DS
// ordering + compiler waitcnts give correctness.
__global__ __launch_bounds__(128, 5) void cv_all(const float* __restrict__ x1,
                                                 const float* __restrict__ x2,
                                                 float* __restrict__ out)
{
    __shared__ __align__(16) float lds[2 * WLDS];   // 2 waves/block -> 8704 B

    const int tx   = threadIdx.x;          // 0..15 -> x quad
    const int ty   = threadIdx.y;          // 0..7  -> y row
    const int tid  = ty * 16 + tx;
    const int lane = tid & 63;
    const int w    = tid >> 6;             // wave 0/1

    // XCD-grouped logical id: 8 XCDs x 320 blocks; consecutive logical
    // blocks (bz fastest, then y0, then d) stay on ONE XCD -> hh re-reads
    // of the same x1/x2 tiles hit that XCD's L2.
    const int lin     = blockIdx.x;                    // 0..2559
    const int logical = (lin & 7) * 320 + (lin >> 3);
    const int bz   = logical % 10;
    const int rest = logical / 10;
    const int y0   = (rest & 7) * 8;
    const int d    = rest >> 3;
    const int b    = bz / 5;
    const int hi   = bz - b * 5;           // 0..4
    const int hh   = hi - 2;               // depth shift in [-2,2]
    const int y    = y0 + ty;
    const int x    = tx * 4;
    const int zd   = d - hh;
    const bool zok = (zd >= 0) && (zd < D_);

    // --- staging geometry: slot A = lane (tile rows 0..3), slot B = lane+64
    const float* x2b = x2 + (size_t)b * CDHW_ + (size_t)(zok ? zd : 0) * HW_;
    const int lrA = lane >> 4,        qA = lane & 15;
    const int lrB = (lane + 64) >> 4, qB = lane & 15;
    const int grA = y0 + 4 * w - 2 + lrA;             // global row, may be <0
    const int grB = y0 + 4 * w - 2 + lrB;             // >=2, may be >=H
    const bool vA = zok && (grA >= 0) && (grA < H_);
    const bool vB = zok && (grB < H_);
    const float* pA = vA ? (x2b + grA * W_ + 4 * qA) : g_zero;
    const float* pB = vB ? (x2b + grB * W_ + 4 * qB) : g_zero;

    const int wbase = w * WLDS;
    const int dA = lrA * BSTR + 2 + 4 * qA;           // dword idx in buffer
    const int dB = lrB * BSTR + 2 + 4 * qB;

    // --- halo cols (idx 0,1,66,67) zero once: 64 slots, one per lane.
    {
        const int half = lane >> 5, rem = lane & 31;
        const int hr = rem >> 2, hc = rem & 3;
        const int hidx = (hc < 2) ? hc : (64 + hc);
        lds[wbase + half * TBUF + hr * BSTR + hidx] = 0.f;
    }

    const float* p1 = x1 + (size_t)b * CDHW_ + (size_t)d * HW_ + (y * W_ + x);
    const int lr0 = ty & 3;                // this lane's tile row - 2

    // --- preamble: c=0 -> buf0; c=1 (SW*), c=2 (SF*) staged in regs
    float4 a0 = *(const float4*)p1;
    float4 a1 = *(const float4*)(p1 + DHW_);
    float4 a2 = *(const float4*)(p1 + 2 * DHW_);
    const float4 L0a = *(const float4*)pA;
    const float4 L0b = *(const float4*)pB;
    float4 SWa = *(const float4*)(pA + (vA ? DHW_ : 0));
    float4 SWb = *(const float4*)(pB + (vB ? DHW_ : 0));
    float4 SFa = *(const float4*)(pA + (vA ? 2 * DHW_ : 0));
    float4 SFb = *(const float4*)(pB + (vB ? 2 * DHW_ : 0));
    {
        float* Wb = lds + wbase;                      // buf0
        *(float2*)(Wb + dA)     = make_float2(L0a.x, L0a.y);
        *(float2*)(Wb + dA + 2) = make_float2(L0a.z, L0a.w);
        *(float2*)(Wb + dB)     = make_float2(L0b.x, L0b.y);
        *(float2*)(Wb + dB + 2) = make_float2(L0b.z, L0b.w);
    }

    float acc[9][4];
#pragma unroll
    for (int k = 0; k < 9; ++k)
#pragma unroll
        for (int j = 0; j < 4; ++j) acc[k][j] = 0.f;

#pragma unroll 2
    for (int c = 0; c < C_; ++c) {
        // 1. write staged data for c+1 (loaded 2 iters ago -> vmcnt slack)
        float* Wb = lds + wbase + ((c + 1) & 1) * TBUF;
        *(float2*)(Wb + dA)     = make_float2(SWa.x, SWa.y);
        *(float2*)(Wb + dA + 2) = make_float2(SWa.z, SWa.w);
        *(float2*)(Wb + dB)     = make_float2(SWb.x, SWb.y);
        *(float2*)(Wb + dB + 2) = make_float2(SWb.z, SWb.w);
        SWa = SFa; SWb = SFb;

        // 2. prefetch c+3 (wraps &63 at tail: harmless valid loads)
        const int off = ((c + 3) & 63) * DHW_;
        SFa = *(const float4*)(pA + (vA ? off : 0));
        SFb = *(const float4*)(pB + (vB ? off : 0));
        const float4 a = a0;
        a0 = a1; a1 = a2;
        a2 = *(const float4*)(p1 + off);

        // 3. compute c from buf[c&1] (written at iter c-1, same wave)
        const float* Bb = lds + wbase + (c & 1) * TBUF;
        float4 k0;
#pragma unroll
        for (int k = 0; k < 5; ++k) {      // rows y-2..y+2, cols x+2..x+5
            const float4 c4 = *(const float4*)(Bb + (lr0 + k) * BSTR + x + 4);
            if (k == 0) k0 = c4;
            const int ai = 4 - k;
            acc[ai][0] += a.x * c4.x;
            acc[ai][1] += a.y * c4.y;
            acc[ai][2] += a.z * c4.z;
            acc[ai][3] += a.w * c4.w;
        }
        const float4 rl = *(const float4*)(Bb + lr0 * BSTR + x);  // cols x-2..x+1
        const float r8[8] = {rl.x, rl.y, rl.z, rl.w, k0.x, k0.y, k0.z, k0.w};
#pragma unroll
        for (int s = 1; s <= 4; ++s) {     // voxel x+v uses r8[4+v-s]
            const int ai = s + 4;
            acc[ai][0] += a.x * r8[4 - s];
            acc[ai][1] += a.y * r8[5 - s];
            acc[ai][2] += a.z * r8[6 - s];
            acc[ai][3] += a.w * r8[7 - s];
        }
    }

    // --- epilogue: 9 live channels + this hi's 16 dead channels
    float* ob = out + (size_t)b * NCH * DHW_ + (size_t)d * HW_ + (y * W_ + x);
    const float inv = 1.0f / 125.0f;
#pragma unroll
    for (int k = 0; k < 9; ++k) {
        const int s = k - 4;
        int ch = 5 * s + hh;
        ch = (ch % NCH + NCH) % NCH;
        float4 v;
        v.x = acc[k][0] * inv;
        v.y = acc[k][1] * inv;
        v.z = acc[k][2] * inv;
        v.w = acc[k][3] * inv;
        *(float4*)(ob + (size_t)ch * DHW_) = v;
    }
    const float4 zero4 = make_float4(0.f, 0.f, 0.f, 0.f);
#pragma unroll
    for (int t = 0; t < 16; ++t) {
        const int ch = 23 + hi * 16 + t;   // hi=0..4 -> 23..102 covered once
        *(float4*)(ob + (size_t)ch * DHW_) = zero4;
    }
}

extern "C" void kernel_launch(void* const* d_in, const int* in_sizes, int n_in,
                              void* d_out, int out_size, void* d_ws, size_t ws_size,
                              hipStream_t stream) {
    const float* x1 = (const float*)d_in[0];
    const float* x2 = (const float*)d_in[1];
    float* out = (float*)d_out;
    // 2560 blocks = 10 per CU, all resident at launch_bounds(128,5) -> no tail
    cv_all<<<dim3(2560, 1, 1), dim3(16, 8, 1), 0, stream>>>(x1, x2, out);
}

// Round 5
// 268.854 us; speedup vs baseline: 1.2638x; 1.0252x over previous
//
#include <hip/hip_runtime.h>

// (B,C,D,H,W) = (2,64,32,64,64), R=2, NCH=125
#define B_ 2
#define C_ 64
#define D_ 32
#define H_ 64
#define W_ 64
#define NCH 125
#define HW_ 4096
#define DHW_ 131072
#define CDHW_ 8388608

// x2 tile per wave: 8 rows x 64 dwords, UNPADDED row-major = exactly the
// global_load_lds "uniform base + lane*16B" layout. 3 buffers (distance-2
// between DMA-write and the ds_reads of the same buffer). 4-dword guards
// front/back absorb the +-2-col halo reads of edge lanes (values masked).
#define TROWS 8
#define TBUF (TROWS * W_)          // 512 dwords per buffer
#define WREG (3 * TBUF)            // per-wave region (3 buffers)

__device__ __attribute__((aligned(16))) const float g_zero[4] = {0.f, 0.f, 0.f, 0.f};

__device__ __forceinline__ void glds16(const float* g, float* l) {
    __builtin_amdgcn_global_load_lds(
        (const __attribute__((address_space(1))) void*)g,
        (__attribute__((address_space(3))) void*)l, 16, 0, 0);
}

// Live offsets form an L: s=i+j in [-4..4], last-write winner is
//   s<=0 -> (i,j)=(s+2,-2): rows y-2..y+2, cols x+2..x+5  (acc[4-k])
//   s>=0 -> (i,j)=(2,s-2) : row y-2, cols x+2-s           (acc[s+4])
// ch=(5s+h) mod 125 -> live {0..22}u{103..124}; 23..102 identically zero.
__global__ __launch_bounds__(128, 5) void cv_all(const float* __restrict__ x1,
                                                 const float* __restrict__ x2,
                                                 float* __restrict__ out)
{
    __shared__ __align__(16) float lds[4 + 2 * WREG + 4];

    const int tid  = threadIdx.y * 16 + threadIdx.x;
    const int lane = tid & 63;
    const int w    = tid >> 6;             // wave 0/1
    const int tx   = lane & 15;            // x quad
    const int lr0  = lane >> 4;            // 0..3: row within wave

    // XCD-grouped swizzle: XCD m owns d-slice [4m,4m+4) -> hh re-reads L2-hit
    const int lin     = blockIdx.x;                    // 0..2559
    const int logical = (lin & 7) * 320 + (lin >> 3);
    const int bz   = logical % 10;
    const int rest = logical / 10;
    const int y0   = (rest & 7) * 8;
    const int d    = rest >> 3;
    const int b    = bz / 5;
    const int hi   = bz - b * 5;           // 0..4
    const int hh   = hi - 2;               // depth shift in [-2,2]
    const int y0w  = y0 + 4 * w;           // wave's first output row
    const int y    = y0w + lr0;
    const int x    = tx * 4;
    const int zd   = d - hh;
    const bool zok = (zd >= 0) && (zd < D_);

    // staging sources: slot A = tile rows 0..3, slot B = rows 4..7
    const float* x2b = x2 + (size_t)b * CDHW_ + (size_t)(zok ? zd : 0) * HW_;
    const int q   = lane & 15;
    const int grA = y0w - 2 + (lane >> 4);             // [-2, 61]
    const int grB = y0w + 2 + (lane >> 4);             // [2, 67]
    const bool vA = zok && (grA >= 0);
    const bool vB = zok && (grB < H_);
    const float* pA = vA ? (x2b + grA * W_ + 4 * q) : g_zero;
    const float* pB = vB ? (x2b + grB * W_ + 4 * q) : g_zero;
    const int sA = vA ? DHW_ : 0;
    const int sB = vB ? DHW_ : 0;

    const int wbase = 4 + w * WREG;
    const float* p1 = x1 + (size_t)b * CDHW_ + (size_t)d * HW_ + (y * W_ + x);

    // dead-channel output base (16 zero channels per hi, spread over loop)
    float* obz = out + (size_t)b * NCH * DHW_ + (size_t)(23 + hi * 16) * DHW_
                     + (size_t)d * HW_ + (y * W_ + x);
    const float4 zero4 = make_float4(0.f, 0.f, 0.f, 0.f);

    // ---- preamble: DMA slab 0 -> buf0; x1 slab 0 -> a0
    glds16(pA, lds + wbase);
    glds16(pB, lds + wbase + TBUF / 2);
    float4 a0 = *(const float4*)p1;
    pA += sA; pB += sB;                    // -> slab 1

    float acc[9][4];
#pragma unroll
    for (int k = 0; k < 9; ++k)
#pragma unroll
        for (int j = 0; j < 4; ++j) acc[k][j] = 0.f;

    const bool lo_edge = (tx == 0);
    const bool hi_edge = (tx == 15);

#pragma unroll 2
    for (int c = 0; c < C_; ++c) {
        // 1. DMA slab c+1 -> buf (c+1)%3 (at c=63: re-DMA slab 63, harmless)
        float* dst = lds + wbase + ((c + 1) % 3) * TBUF;
        glds16(pA, dst);
        glds16(pB, dst + TBUF / 2);
        // 2. x1 slab c+1 (wraps to 0 at tail, harmless in-bounds load)
        float4 a1 = *(const float4*)(p1 + (size_t)((c + 1) & 63) * DHW_);
        if (c < 62) { pA += sA; pB += sB; }

        // 3. gate: allow this iter's 3 VMEM in flight; require buf(c) + a0 done
        asm volatile("s_waitcnt vmcnt(3)" ::: "memory");

        // 4. compute c from buf c%3
        const float* Bb = lds + wbase + (c % 3) * TBUF;
        const float4 a = a0;
        float2 k0A, k0B;
#pragma unroll
        for (int k = 0; k < 5; ++k) {      // tile rows lr0..lr0+4 = y-2..y+2
            const float* pr = Bb + (lr0 + k) * W_ + x;
            const float2 cA = *(const float2*)(pr + 2);   // cols x+2,x+3
            float2 cB = *(const float2*)(pr + 4);         // cols x+4,x+5
            cB.x = hi_edge ? 0.f : cB.x;   // cols 64,65 don't exist
            cB.y = hi_edge ? 0.f : cB.y;
            if (k == 0) { k0A = cA; k0B = cB; }
            const int ai = 4 - k;
            acc[ai][0] += a.x * cA.x;
            acc[ai][1] += a.y * cA.y;
            acc[ai][2] += a.z * cB.x;
            acc[ai][3] += a.w * cB.y;
        }
        {                                  // row part: tile row lr0 = y-2
            const float* pr = Bb + lr0 * W_ + x;
            float2 rlA = *(const float2*)(pr - 2);        // cols x-2,x-1
            const float2 rlB = *(const float2*)(pr);      // cols x,x+1
            rlA.x = lo_edge ? 0.f : rlA.x; // cols -2,-1 don't exist
            rlA.y = lo_edge ? 0.f : rlA.y;
            const float r8[8] = {rlA.x, rlA.y, rlB.x, rlB.y,
                                 k0A.x, k0A.y, k0B.x, k0B.y};
#pragma unroll
            for (int s = 1; s <= 4; ++s) { // voxel x+v uses r8[4+v-s]
                const int ai = s + 4;
                acc[ai][0] += a.x * r8[4 - s];
                acc[ai][1] += a.y * r8[5 - s];
                acc[ai][2] += a.z * r8[6 - s];
                acc[ai][3] += a.w * r8[7 - s];
            }
        }
        a0 = a1;

        // 5. spread the 16 dead-channel zero stores across the loop
        if ((c & 3) == 0)
            *(float4*)(obz + (size_t)(c >> 2) * DHW_) = zero4;
    }

    // ---- epilogue: 9 live channels
    float* ob = out + (size_t)b * NCH * DHW_ + (size_t)d * HW_ + (y * W_ + x);
    const float inv = 1.0f / 125.0f;
#pragma unroll
    for (int k = 0; k < 9; ++k) {
        const int s = k - 4;
        int ch = 5 * s + hh;
        ch = (ch % NCH + NCH) % NCH;
        float4 v;
        v.x = acc[k][0] * inv;
        v.y = acc[k][1] * inv;
        v.z = acc[k][2] * inv;
        v.w = acc[k][3] * inv;
        *(float4*)(ob + (size_t)ch * DHW_) = v;
    }
}

extern "C" void kernel_launch(void* const* d_in, const int* in_sizes, int n_in,
                              void* d_out, int out_size, void* d_ws, size_t ws_size,
                              hipStream_t stream) {
    const float* x1 = (const float*)d_in[0];
    const float* x2 = (const float*)d_in[1];
    float* out = (float*)d_out;
    // 2560 blocks x 2 waves = 20 waves/CU, all resident
    cv_all<<<dim3(2560, 1, 1), dim3(16, 8, 1), 0, stream>>>(x1, x2, out);
}